// Round 16
// baseline (889.314 us; speedup 1.0000x reference)
//
#include <hip/hip_runtime.h>
#include <hip/hip_bf16.h>
#include <math.h>

#define EMB 128
#define CDIM 12
#define FIN 16
#define NLAYER 5
#define BN_EPS 1e-5f

typedef __attribute__((ext_vector_type(8))) _Float16 f16x8;
typedef __attribute__((ext_vector_type(2))) __fp16 fp16v2;
typedef __attribute__((ext_vector_type(4))) float f32x4;
typedef unsigned short ushort_t;

union h2u { fp16v2 h; unsigned u; };
union hu  { _Float16 h; ushort_t u; };

// exact fp32 -> fp16 hi/lo split for a pair: hi = RTZ-pack, lo = RTZ(residual).
__device__ __forceinline__ void fsplit2(float a, float b, unsigned& hi, unsigned& lo) {
    h2u H; H.h = __builtin_amdgcn_cvt_pkrtz(a, b);
    float r0 = a - (float)H.h.x;
    float r1 = b - (float)H.h.y;
    h2u L; L.h = __builtin_amdgcn_cvt_pkrtz(r0, r1);
    hi = H.u; lo = L.u;
}

// pack 2 floats to 2 fp16 with round-to-nearest
__device__ __forceinline__ unsigned pkrn(float x, float y) {
    hu A; A.h = (_Float16)x;
    hu B; B.h = (_Float16)y;
    return (unsigned)A.u | ((unsigned)B.u << 16);
}

// accumulate 8 fp16 (packed in uint4) into f[0..7]
__device__ __forceinline__ void acc8(float* f, uint4 v) {
    h2u c0, c1, c2, c3;
    c0.u = v.x; c1.u = v.y; c2.u = v.z; c3.u = v.w;
    f[0] += (float)c0.h.x; f[1] += (float)c0.h.y;
    f[2] += (float)c1.h.x; f[3] += (float)c1.h.y;
    f[4] += (float)c2.h.x; f[5] += (float)c2.h.y;
    f[6] += (float)c3.h.x; f[7] += (float)c3.h.y;
}

// LDS tile address: logical [node][byteoff 0..255], XOR-swizzled for bank spread.
__device__ __forceinline__ unsigned swz(int node, unsigned byteoff) {
    return (unsigned)(node * 256 + byteoff) ^ (((unsigned)node & 7u) << 4);
}

// ---------------- graph preprocessing ----------------

__global__ __launch_bounds__(256) void k_gstart(const int* __restrict__ batch,
                                                int* __restrict__ gs, int N, int G) {
    int i = blockIdx.x * 256 + threadIdx.x;
    if (i >= N) return;
    if (i == 0) gs[0] = 0;
    else { int b = batch[i]; if (b != batch[i - 1]) gs[b] = i; }
    if (i == N - 1) gs[G] = N;
}

__global__ __launch_bounds__(256) void k_zero_i32(int* __restrict__ p, int n) {
    int i = blockIdx.x * 256 + threadIdx.x;
    if (i < n) p[i] = 0;
}

__global__ __launch_bounds__(256) void k_fill_i32(int* __restrict__ p, int val, int n) {
    int i = blockIdx.x * 256 + threadIdx.x;
    if (i < n) p[i] = val;
}

__global__ __launch_bounds__(256) void k_zero_f32(float* __restrict__ p, int n) {
    int i = blockIdx.x * 256 + threadIdx.x;
    if (i < n) p[i] = 0.f;
}

__global__ __launch_bounds__(128) void k_zero_dummy(ushort_t* __restrict__ a,
                                                    ushort_t* __restrict__ b, int N) {
    int i = threadIdx.x;
    a[(size_t)N * EMB + i] = 0;
    b[(size_t)N * EMB + i] = 0;
}

__global__ __launch_bounds__(256) void k_hist(const int* __restrict__ dst, int* __restrict__ cnt, int E) {
    int e = blockIdx.x * 256 + threadIdx.x;
    if (e < E) atomicAdd(&cnt[dst[e]], 1);
}

// scans over N+1 entries; per-node counts PADDED to multiples of 4 -> rs[N] = padded total
__global__ __launch_bounds__(256) void k_scan1(const int* __restrict__ cnt, int* __restrict__ rs,
                                               int* __restrict__ partials, int N) {
    __shared__ int tsum[256];
    int t = threadIdx.x;
    int base = blockIdx.x * 1024 + t * 4;
    int c[4];
    #pragma unroll
    for (int j = 0; j < 4; j++) c[j] = (base + j < N) ? ((cnt[base + j] + 3) & ~3) : 0;
    int s = c[0] + c[1] + c[2] + c[3];
    tsum[t] = s;
    __syncthreads();
    for (int off = 1; off < 256; off <<= 1) {
        int v = (t >= off) ? tsum[t - off] : 0;
        __syncthreads();
        tsum[t] += v;
        __syncthreads();
    }
    int run = tsum[t] - s;
    if (t == 255) partials[blockIdx.x] = tsum[255];
    #pragma unroll
    for (int j = 0; j < 4; j++) {
        if (base + j <= N) rs[base + j] = run;
        run += c[j];
    }
}

__global__ __launch_bounds__(256) void k_scan2(int* __restrict__ partials, int NB) {
    __shared__ int tmp[256];
    int t = threadIdx.x;
    int v = (t < NB) ? partials[t] : 0;
    tmp[t] = v;
    __syncthreads();
    for (int off = 1; off < 256; off <<= 1) {
        int u = (t >= off) ? tmp[t - off] : 0;
        __syncthreads();
        tmp[t] += u;
        __syncthreads();
    }
    if (t < NB) partials[t] = tmp[t] - v;
}

__global__ __launch_bounds__(256) void k_scan3(int* __restrict__ rs, const int* __restrict__ partials,
                                               int* __restrict__ cur_off, int N) {
    int t = threadIdx.x;
    int base = blockIdx.x * 1024 + t * 4;
    int add = partials[blockIdx.x];
    #pragma unroll
    for (int j = 0; j < 4; j++) {
        int i = base + j;
        if (i <= N) {
            int v = rs[i] + add;
            rs[i] = v;
            if (i < N) cur_off[i] = v;
        }
    }
}

__global__ __launch_bounds__(256) void k_fillslots(const int* __restrict__ src, const int* __restrict__ dst,
                                                   int* __restrict__ cur_off, int* __restrict__ csr_src, int E) {
    int e = blockIdx.x * 256 + threadIdx.x;
    if (e >= E) return;
    int d = dst[e];
    int pos = atomicAdd(&cur_off[d], 1);
    csr_src[pos] = src[e];
}

// ---------------- weight prep: fold BN, transpose, convert to fp16 (RN) ----------------

__global__ __launch_bounds__(256) void k_prep(
        const float* __restrict__ init_w1, const float* __restrict__ init_b1,
        const float* __restrict__ b1s, const float* __restrict__ b1b,
        const float* __restrict__ b1m, const float* __restrict__ b1v,
        const float* __restrict__ init_w2, const float* __restrict__ init_b2,
        const float* __restrict__ i_s, const float* __restrict__ i_b,
        const float* __restrict__ i_m, const float* __restrict__ i_v,
        const float* __restrict__ lw1, const float* __restrict__ lb1,
        const float* __restrict__ l1s, const float* __restrict__ l1b,
        const float* __restrict__ l1m, const float* __restrict__ l1v,
        const float* __restrict__ lw2, const float* __restrict__ lb2,
        const float* __restrict__ l2s, const float* __restrict__ l2b,
        const float* __restrict__ l2m, const float* __restrict__ l2v,
        const float* __restrict__ ilin_w, const float* __restrict__ ilin_b,
        ushort_t* __restrict__ WT, float* __restrict__ biasf,
        float* __restrict__ W1f, float* __restrict__ bias1f,
        ushort_t* __restrict__ WzT, float* __restrict__ biasz) {
    int j = blockIdx.x;
    int t = threadIdx.x;
    __shared__ float alpha[EMB];

    if (j == 12) {
        if (t < 16) biasz[t] = (t < CDIM) ? ilin_b[t] : 0.f;
        for (int i = t; i < 16 * EMB; i += 256) {
            int f = i >> 7, k = i & 127;
            float w = (f < CDIM) ? ilin_w[k * CDIM + f] : 0.f;
            hu x; x.h = (_Float16)w;
            WzT[i] = x.u;
        }
        return;
    }
    if (j == 11) {
        if (t < EMB) {
            float a = b1s[t] * rsqrtf(b1v[t] + BN_EPS);
            alpha[t] = a;
            bias1f[t] = init_b1[t] * a + (b1b[t] - b1m[t] * a);
        }
        __syncthreads();
        for (int i = t; i < FIN * EMB; i += 256) W1f[i] = init_w1[i] * alpha[i & 127];
        return;
    }

    const float *W, *lb, *s, *bb, *m, *v;
    if (j == 0)      { W = init_w2;            lb = init_b2;        s = i_s;           bb = i_b;           m = i_m;           v = i_v; }
    else if (j <= 5) { int l = j - 1; W = lw1 + l * 16384; lb = lb1 + l * 128; s = l1s + l * 128; bb = l1b + l * 128; m = l1m + l * 128; v = l1v + l * 128; }
    else             { int l = j - 6; W = lw2 + l * 16384; lb = lb2 + l * 128; s = l2s + l * 128; bb = l2b + l * 128; m = l2m + l * 128; v = l2v + l * 128; }
    if (t < EMB) {
        float a = s[t] * rsqrtf(v[t] + BN_EPS);
        alpha[t] = a;
        biasf[j * EMB + t] = lb[t] * a + (bb[t] - m[t] * a);
    }
    __syncthreads();
    for (int i = t; i < EMB * EMB; i += 256) {
        int k = i >> 7, f = i & 127;
        float w = W[i] * alpha[f];
        hu x; x.h = (_Float16)w;
        WT[j * 16384 + f * 128 + k] = x.u;
    }
}

// ---------------- fused layer kernel ----------------
// h stored globally as fp16 [N+1][128] (row N = zero dummy for CSR pads).
// MODE 0 (init, NT=16): phaseA = relu(bn(x@W1)); gemm(init_w2) -> h(fp16) + LDSB; wave0: z-gemm
// MODE 1 (GIN, NT=64):  each thread gathers TWO nodes (independent chains -> ILP);
//                       64KB LDS -> 2 blocks/CU (16 waves); 2x MFMA per barrier.
//                       gemm1 -> LDSB; gemm2 -> h'(fp16, opt) + fused shfl-segmax -> smax.

template<int MODE>
__global__ __launch_bounds__(512, 4) void k_layer(
        const float* __restrict__ xin, const ushort_t* __restrict__ hin,
        ushort_t* __restrict__ hout, float* __restrict__ z,
        const ushort_t* __restrict__ W1T, const float* __restrict__ b1,
        const ushort_t* __restrict__ W2T, const float* __restrict__ b2,
        const ushort_t* __restrict__ WzT, const float* __restrict__ bz,
        const float* __restrict__ W1f, const float* __restrict__ b1f,
        const int* __restrict__ rs, const int* __restrict__ csr, const float* __restrict__ epsp,
        const int* __restrict__ batch, float* __restrict__ smax,
        int ntiles, int N) {
    constexpr int NT = (MODE == 1) ? 64 : 16;
    constexpr int NSUB = (MODE == 1) ? 4 : 1;
    __shared__ ushort_t Ah[NT * 128], Al[NT * 128], Bh_[NT * 128], Bl_[NT * 128];
    __shared__ float W1s[(MODE == 0) ? FIN * EMB : 1];

    const int t = threadIdx.x;
    const int w = t >> 6;
    const int lane = t & 63;
    const int col = lane & 15, kg = lane >> 4;

    if (MODE == 0) {
        for (int i = t; i < FIN * EMB; i += 512) W1s[i] = W1f[i];
        __syncthreads();
    }

    // register-resident weight fragments (single fp16 per matrix: 16 regs each)
    f16x8 w1f[4], w2f[4], wzf[4];
    #pragma unroll
    for (int s = 0; s < 4; s++) {
        int off = (w * 16 + col) * EMB + s * 32 + kg * 8;
        w1f[s] = *(const f16x8*)(W1T + off);
        if (MODE == 1) w2f[s] = *(const f16x8*)(W2T + off);
        if (MODE == 0) {
            int zoff = col * EMB + s * 32 + kg * 8;
            wzf[s] = *(const f16x8*)(WzT + zoff);
        }
    }
    float4 bv1 = *(const float4*)&b1[w * 16 + kg * 4];
    float4 bv2, bvz;
    if (MODE == 1) bv2 = *(const float4*)&b2[w * 16 + kg * 4];
    if (MODE == 0) bvz = *(const float4*)&bz[kg * 4];
    float se = (MODE == 1) ? (1.f + epsp[0]) : 0.f;

    const int nlp = t >> 4, q2p = t & 15;

    for (int tile = blockIdx.x; tile < ntiles; tile += gridDim.x) {
        const int n0 = tile * NT;

        // ---- phase A -> LDSA (fp16 hi/lo of the fp32 aggregate) ----
        if (MODE == 1) {
            const uint4* hp = (const uint4*)hin;
            // two independent gather chains per thread (nodes nlp and nlp+32)
            const int ncA = min(n0 + nlp, N - 1);
            const int ncB = min(n0 + nlp + 32, N - 1);
            uint4 svA = hp[(size_t)ncA * 16 + q2p];
            uint4 svB = hp[(size_t)ncB * 16 + q2p];
            int pA = rs[ncA], peA = rs[ncA + 1];
            int pB = rs[ncB], peB = rs[ncB + 1];
            uint4 iA, iB;
            if (pA < peA) iA = *(const uint4*)&csr[pA];
            else { iA.x = iA.y = iA.z = iA.w = (unsigned)N; }
            if (pB < peB) iB = *(const uint4*)&csr[pB];
            else { iB.x = iB.y = iB.z = iB.w = (unsigned)N; }
            uint4 rA0 = hp[(size_t)iA.x * 16 + q2p], rA1 = hp[(size_t)iA.y * 16 + q2p];
            uint4 rA2 = hp[(size_t)iA.z * 16 + q2p], rA3 = hp[(size_t)iA.w * 16 + q2p];
            uint4 rB0 = hp[(size_t)iB.x * 16 + q2p], rB1 = hp[(size_t)iB.y * 16 + q2p];
            uint4 rB2 = hp[(size_t)iB.z * 16 + q2p], rB3 = hp[(size_t)iB.w * 16 + q2p];

            float a[8] = {0.f,0.f,0.f,0.f,0.f,0.f,0.f,0.f};
            float b[8] = {0.f,0.f,0.f,0.f,0.f,0.f,0.f,0.f};
            acc8(a, svA); acc8(b, svB);
            #pragma unroll
            for (int i = 0; i < 8; i++) { a[i] *= se; b[i] *= se; }
            acc8(a, rA0); acc8(a, rA1); acc8(a, rA2); acc8(a, rA3);
            acc8(b, rB0); acc8(b, rB1); acc8(b, rB2); acc8(b, rB3);
            for (int p = pA + 4; p < peA; p += 4) {   // deg>4 tail (rare)
                uint4 idx = *(const uint4*)&csr[p];
                acc8(a, hp[(size_t)idx.x * 16 + q2p]); acc8(a, hp[(size_t)idx.y * 16 + q2p]);
                acc8(a, hp[(size_t)idx.z * 16 + q2p]); acc8(a, hp[(size_t)idx.w * 16 + q2p]);
            }
            for (int p = pB + 4; p < peB; p += 4) {
                uint4 idx = *(const uint4*)&csr[p];
                acc8(b, hp[(size_t)idx.x * 16 + q2p]); acc8(b, hp[(size_t)idx.y * 16 + q2p]);
                acc8(b, hp[(size_t)idx.z * 16 + q2p]); acc8(b, hp[(size_t)idx.w * 16 + q2p]);
            }
            uint4 H, L;
            fsplit2(a[0], a[1], H.x, L.x); fsplit2(a[2], a[3], H.y, L.y);
            fsplit2(a[4], a[5], H.z, L.z); fsplit2(a[6], a[7], H.w, L.w);
            unsigned ad = swz(nlp, (unsigned)q2p * 16);
            *(uint4*)((char*)Ah + ad) = H;
            *(uint4*)((char*)Al + ad) = L;
            fsplit2(b[0], b[1], H.x, L.x); fsplit2(b[2], b[3], H.y, L.y);
            fsplit2(b[4], b[5], H.z, L.z); fsplit2(b[6], b[7], H.w, L.w);
            ad = swz(nlp + 32, (unsigned)q2p * 16);
            *(uint4*)((char*)Ah + ad) = H;
            *(uint4*)((char*)Al + ad) = L;
        } else {
            const int nl = t >> 5, q = t & 31;    // 16 nodes x 4 feats
            const int nc = min(n0 + nl, N - 1);
            float4 ba = *(const float4*)&b1f[q * 4];
            float a0 = ba.x, a1 = ba.y, a2 = ba.z, a3 = ba.w;
            const float* xp = xin + (size_t)nc * FIN;
            #pragma unroll
            for (int k = 0; k < FIN; k++) {
                float xk = xp[k];
                float4 wv = *(const float4*)&W1s[k * EMB + q * 4];
                a0 += xk * wv.x; a1 += xk * wv.y; a2 += xk * wv.z; a3 += xk * wv.w;
            }
            a0 = fmaxf(a0, 0.f); a1 = fmaxf(a1, 0.f); a2 = fmaxf(a2, 0.f); a3 = fmaxf(a3, 0.f);
            uint2 H, L;
            fsplit2(a0, a1, H.x, L.x);
            fsplit2(a2, a3, H.y, L.y);
            unsigned ad = swz(nl, (unsigned)q * 8);
            *(uint2*)((char*)Ah + ad) = H;
            *(uint2*)((char*)Al + ad) = L;
        }
        __syncthreads();

        // ---- phase B: gemm1 from LDSA -> LDSB (MODE0: + hout fp16 store) ----
        {
            f32x4 aA[NSUB], aB[NSUB];
            #pragma unroll
            for (int j = 0; j < NSUB; j++) { aA[j] = (f32x4){0.f,0.f,0.f,0.f}; aB[j] = aA[j]; }
            #pragma unroll
            for (int s = 0; s < 4; s++) {
                unsigned bo = (unsigned)((s * 32 + kg * 8) * 2);
                #pragma unroll
                for (int j = 0; j < NSUB; j++) {
                    f16x8 xh = *(const f16x8*)((const char*)Ah + swz(col + j * 16, bo));
                    f16x8 xl = *(const f16x8*)((const char*)Al + swz(col + j * 16, bo));
                    aA[j] = __builtin_amdgcn_mfma_f32_16x16x32_f16(w1f[s], xh, aA[j], 0, 0, 0);
                    aB[j] = __builtin_amdgcn_mfma_f32_16x16x32_f16(w1f[s], xl, aB[j], 0, 0, 0);
                }
            }
            #pragma unroll
            for (int j = 0; j < NSUB; j++) {
                float y0 = fmaxf(aA[j][0] + aB[j][0] + bv1.x, 0.f);
                float y1 = fmaxf(aA[j][1] + aB[j][1] + bv1.y, 0.f);
                float y2 = fmaxf(aA[j][2] + aB[j][2] + bv1.z, 0.f);
                float y3 = fmaxf(aA[j][3] + aB[j][3] + bv1.w, 0.f);
                if (MODE == 0) {
                    int onode = n0 + col;
                    if (onode < N) {
                        uint2 P; P.x = pkrn(y0, y1); P.y = pkrn(y2, y3);
                        *(uint2*)&hout[(size_t)onode * EMB + w * 16 + kg * 4] = P;
                    }
                }
                uint2 H, L;
                fsplit2(y0, y1, H.x, L.x);
                fsplit2(y2, y3, H.y, L.y);
                unsigned ad = swz(col + j * 16, (unsigned)(w * 32 + kg * 8));
                *(uint2*)((char*)Bh_ + ad) = H;
                *(uint2*)((char*)Bl_ + ad) = L;
            }
        }
        __syncthreads();

        // ---- phase D: gemm2 + fused segmax (MODE1) / z-gemm (MODE0, wave0) ----
        if (MODE == 1) {
            f32x4 aA[NSUB], aB[NSUB];
            #pragma unroll
            for (int j = 0; j < NSUB; j++) { aA[j] = (f32x4){0.f,0.f,0.f,0.f}; aB[j] = aA[j]; }
            #pragma unroll
            for (int s = 0; s < 4; s++) {
                unsigned bo = (unsigned)((s * 32 + kg * 8) * 2);
                #pragma unroll
                for (int j = 0; j < NSUB; j++) {
                    f16x8 xh = *(const f16x8*)((const char*)Bh_ + swz(col + j * 16, bo));
                    f16x8 xl = *(const f16x8*)((const char*)Bl_ + swz(col + j * 16, bo));
                    aA[j] = __builtin_amdgcn_mfma_f32_16x16x32_f16(w2f[s], xh, aA[j], 0, 0, 0);
                    aB[j] = __builtin_amdgcn_mfma_f32_16x16x32_f16(w2f[s], xl, aB[j], 0, 0, 0);
                }
            }
            #pragma unroll
            for (int j = 0; j < NSUB; j++) {
                int onode = n0 + col + j * 16;
                float o0 = fmaxf(aA[j][0] + aB[j][0] + bv2.x, 0.f);
                float o1 = fmaxf(aA[j][1] + aB[j][1] + bv2.y, 0.f);
                float o2 = fmaxf(aA[j][2] + aB[j][2] + bv2.z, 0.f);
                float o3 = fmaxf(aA[j][3] + aB[j][3] + bv2.w, 0.f);
                if (hout && onode < N) {
                    uint2 P; P.x = pkrn(o0, o1); P.y = pkrn(o2, o3);
                    *(uint2*)&hout[(size_t)onode * EMB + w * 16 + kg * 4] = P;
                }
                // fused segment-max: width-16 segmented scan-max, tail lanes do atomicMax.
                bool valid = onode < N;
                float v0 = valid ? o0 : 0.f, v1 = valid ? o1 : 0.f;
                float v2 = valid ? o2 : 0.f, v3 = valid ? o3 : 0.f;
                int g = batch[min(onode, N - 1)];
                #pragma unroll
                for (int off = 1; off < 16; off <<= 1) {
                    float u0 = __shfl_up(v0, off, 16);
                    float u1 = __shfl_up(v1, off, 16);
                    float u2 = __shfl_up(v2, off, 16);
                    float u3 = __shfl_up(v3, off, 16);
                    int gg = __shfl_up(g, off, 16);
                    bool take = (col >= off) && (gg == g);
                    if (take) {
                        v0 = fmaxf(v0, u0); v1 = fmaxf(v1, u1);
                        v2 = fmaxf(v2, u2); v3 = fmaxf(v3, u3);
                    }
                }
                int gn = __shfl_down(g, 1, 16);
                bool tail = (col == 15) || (gn != g);
                if (tail) {
                    unsigned* sp = (unsigned*)&smax[(size_t)g * EMB + w * 16 + kg * 4];
                    atomicMax(sp + 0, __float_as_uint(v0));
                    atomicMax(sp + 1, __float_as_uint(v1));
                    atomicMax(sp + 2, __float_as_uint(v2));
                    atomicMax(sp + 3, __float_as_uint(v3));
                }
            }
        } else if (w == 0) {
            f32x4 aA0 = (f32x4){0.f, 0.f, 0.f, 0.f}, aB0 = aA0;
            #pragma unroll
            for (int s = 0; s < 4; s++) {
                unsigned bo = (unsigned)((s * 32 + kg * 8) * 2);
                f16x8 xh = *(const f16x8*)((const char*)Bh_ + swz(col, bo));
                f16x8 xl = *(const f16x8*)((const char*)Bl_ + swz(col, bo));
                aA0 = __builtin_amdgcn_mfma_f32_16x16x32_f16(wzf[s], xh, aA0, 0, 0, 0);
                aB0 = __builtin_amdgcn_mfma_f32_16x16x32_f16(wzf[s], xl, aB0, 0, 0, 0);
            }
            int onode = n0 + col;
            if (onode < N && kg < 3) {
                float4 o;
                o.x = aA0[0] + aB0[0] + bvz.x;
                o.y = aA0[1] + aB0[1] + bvz.y;
                o.z = aA0[2] + aB0[2] + bvz.z;
                o.w = aA0[3] + aB0[3] + bvz.w;
                *(float4*)&z[(size_t)onode * CDIM + kg * 4] = o;
            }
        }
        // no trailing barrier: next-tile A-writes gated by this tile's post-B barrier
        // (A last read in phase B); B-writes gated by next post-A barrier.
    }
}

// ---------------- readouts ----------------

__global__ __launch_bounds__(64) void k_zmax(const float* __restrict__ z, const int* __restrict__ gs,
        float* __restrict__ out, int G) {
    int g = blockIdx.x;
    int t = threadIdx.x;
    if (t >= CDIM) return;
    int s0 = gs[g], e0 = gs[g + 1];
    float m = -INFINITY;
    for (int n = s0; n < e0; n++) m = fmaxf(m, z[(size_t)n * CDIM + t]);
    out[g * CDIM + t] = m;
}

// out[g,c] += sum_l ( smax_l[g,:] @ llin_w[l] + llin_b[l] )
__global__ __launch_bounds__(128) void k_comb(const float* __restrict__ smax,
        const float* __restrict__ llin_w, const float* __restrict__ llin_b,
        float* __restrict__ out, int G) {
    int g = blockIdx.x;
    int t = threadIdx.x;
    __shared__ float mv[NLAYER][EMB];
    #pragma unroll
    for (int l = 0; l < NLAYER; l++)
        mv[l][t] = smax[((size_t)l * G + g) * EMB + t];
    __syncthreads();
    __shared__ float parts_[8][16];
    int c = t & 15, half = t >> 4;
    float acc = 0.f;
    if (c < CDIM) {
        #pragma unroll
        for (int l = 0; l < NLAYER; l++) {
            const float* Wl = llin_w + l * EMB * CDIM;
            #pragma unroll
            for (int kk = 0; kk < 16; kk++) {
                int k = half * 16 + kk;
                acc += mv[l][k] * Wl[k * CDIM + c];
            }
        }
    }
    parts_[half][c] = acc;
    __syncthreads();
    if (t < CDIM) {
        float s = 0.f;
        #pragma unroll
        for (int hh = 0; hh < 8; hh++) s += parts_[hh][t];
        #pragma unroll
        for (int l = 0; l < NLAYER; l++) s += llin_b[l * CDIM + t];
        out[g * CDIM + t] += s;
    }
}

// ---------------- launch ----------------

extern "C" void kernel_launch(void* const* d_in, const int* in_sizes, int n_in,
                              void* d_out, int out_size, void* d_ws, size_t ws_size,
                              hipStream_t stream) {
    const float* x        = (const float*)d_in[0];
    const int*   ei       = (const int*)d_in[1];
    const int*   batch    = (const int*)d_in[2];
    const float* init_w1  = (const float*)d_in[3];
    const float* init_b1  = (const float*)d_in[4];
    const float* ibn1_s   = (const float*)d_in[5];
    const float* ibn1_b   = (const float*)d_in[6];
    const float* ibn1_m   = (const float*)d_in[7];
    const float* ibn1_v   = (const float*)d_in[8];
    const float* init_w2  = (const float*)d_in[9];
    const float* init_b2  = (const float*)d_in[10];
    const float* ibn2_s   = (const float*)d_in[11];
    const float* ibn2_b   = (const float*)d_in[12];
    const float* ibn2_m   = (const float*)d_in[13];
    const float* ibn2_v   = (const float*)d_in[14];
    const float* ilin_w   = (const float*)d_in[15];
    const float* ilin_b   = (const float*)d_in[16];
    const float* eps      = (const float*)d_in[17];
    const float* lw1      = (const float*)d_in[18];
    const float* lb1      = (const float*)d_in[19];
    const float* lbn1_s   = (const float*)d_in[20];
    const float* lbn1_b   = (const float*)d_in[21];
    const float* lbn1_m   = (const float*)d_in[22];
    const float* lbn1_v   = (const float*)d_in[23];
    const float* lw2      = (const float*)d_in[24];
    const float* lb2      = (const float*)d_in[25];
    const float* lbn2_s   = (const float*)d_in[26];
    const float* lbn2_b   = (const float*)d_in[27];
    const float* lbn2_m   = (const float*)d_in[28];
    const float* lbn2_v   = (const float*)d_in[29];
    const float* llin_w   = (const float*)d_in[30];
    const float* llin_b   = (const float*)d_in[31];

    const int N = in_sizes[0] / FIN;
    const int E = in_sizes[1] / 2;
    const int G = out_size / CDIM;
    const int* src = ei;
    const int* dst = ei + E;
    float* out = (float*)d_out;

    const int EPADMAX = E + 3 * N;

    char* wp = (char*)d_ws;
    auto alloc = [&](size_t bytes) { char* p = wp; wp += (bytes + 255) & ~(size_t)255; return p; };
    ushort_t* WT    = (ushort_t*)alloc((size_t)11 * 16384 * 2);
    float*    biasf = (float*)alloc(11 * EMB * 4);
    float*    W1f   = (float*)alloc(FIN * EMB * 4);
    float*    bias1f= (float*)alloc(EMB * 4);
    ushort_t* WzT   = (ushort_t*)alloc(16 * EMB * 2);
    float*    biasz = (float*)alloc(16 * 4);
    int*      gs    = (int*)alloc((size_t)(G + 1) * 4);
    int*      rs    = (int*)alloc((size_t)(N + 1) * 4);
    int*      curoff= (int*)alloc((size_t)N * 4);
    int*      csr   = (int*)alloc((size_t)EPADMAX * 4);
    int*      parts = (int*)alloc(256 * 4);
    float*    zbuf  = (float*)alloc((size_t)N * CDIM * 4);
    float*    smax  = (float*)alloc((size_t)NLAYER * G * EMB * 4);
    ushort_t* bufP  = (ushort_t*)alloc((size_t)(N + 1) * EMB * 2);   // row N = zero dummy
    ushort_t* bufQ  = (ushort_t*)alloc((size_t)(N + 1) * EMB * 2);
    int*      cnt   = csr;           // alias: cnt dead before csr pre-filled

    const int NB = (N + 1 + 1023) / 1024;
    const int ntiles16 = (N + 15) / 16;
    const int ntiles64 = (N + 63) / 64;
    const int GRID0 = 2084;
    const int GRID1 = (ntiles64 + 1) / 2;   // 2 tiles/block

    // per-call inits (smax: atomicMax with non-negative floats; zero is identity)
    k_zero_f32<<<((NLAYER * G * EMB) + 255) / 256, 256, 0, stream>>>(smax, NLAYER * G * EMB);
    k_zero_dummy<<<1, 128, 0, stream>>>(bufP, bufQ, N);

    // graph prep (padded CSR) + weight prep
    k_zero_i32<<<(N + 255) / 256, 256, 0, stream>>>(cnt, N);
    k_hist<<<(E + 255) / 256, 256, 0, stream>>>(dst, cnt, E);
    k_scan1<<<NB, 256, 0, stream>>>(cnt, rs, parts, N);
    k_scan2<<<1, 256, 0, stream>>>(parts, NB);
    k_scan3<<<NB, 256, 0, stream>>>(rs, parts, curoff, N);
    k_fill_i32<<<(EPADMAX + 255) / 256, 256, 0, stream>>>(csr, N, EPADMAX);  // pads -> zero row N
    k_fillslots<<<(E + 255) / 256, 256, 0, stream>>>(src, dst, curoff, csr, E);
    k_gstart<<<(N + 255) / 256, 256, 0, stream>>>(batch, gs, N, G);
    k_prep<<<13, 256, 0, stream>>>(init_w1, init_b1, ibn1_s, ibn1_b, ibn1_m, ibn1_v,
                                   init_w2, init_b2, ibn2_s, ibn2_b, ibn2_m, ibn2_v,
                                   lw1, lb1, lbn1_s, lbn1_b, lbn1_m, lbn1_v,
                                   lw2, lb2, lbn2_s, lbn2_b, lbn2_m, lbn2_v,
                                   ilin_w, ilin_b,
                                   WT, biasf, W1f, bias1f, WzT, biasz);

    // init MLP + z (fused) -> h(fp16) in bufQ, z in zbuf
    k_layer<0><<<GRID0, 512, 0, stream>>>(x, nullptr, bufQ, zbuf,
                                          WT, biasf,
                                          nullptr, nullptr,
                                          WzT, biasz,
                                          W1f, bias1f,
                                          nullptr, nullptr, nullptr,
                                          nullptr, nullptr, ntiles16, N);
    k_zmax<<<G, 64, 0, stream>>>(zbuf, gs, out, G);

    ushort_t* cur = bufQ;
    ushort_t* oth = bufP;
    for (int l = 0; l < NLAYER; l++) {
        ushort_t* houtl = (l == NLAYER - 1) ? nullptr : oth;   // last layer: segmax only
        k_layer<1><<<GRID1, 512, 0, stream>>>(nullptr, cur, houtl, nullptr,
                                              WT + (size_t)(1 + l) * 16384, biasf + (1 + l) * EMB,
                                              WT + (size_t)(6 + l) * 16384, biasf + (6 + l) * EMB,
                                              nullptr, nullptr,
                                              nullptr, nullptr,
                                              rs, csr, eps + l,
                                              batch, smax + (size_t)l * G * EMB, ntiles64, N);
        ushort_t* tmp = cur; cur = oth; oth = tmp;
    }
    k_comb<<<G, 128, 0, stream>>>(smax, llin_w, llin_b, out, G);
}

// Round 17
// 658.421 us; speedup vs baseline: 1.3507x; 1.3507x over previous
//
#include <hip/hip_runtime.h>
#include <hip/hip_bf16.h>
#include <math.h>

#define EMB 128
#define CDIM 12
#define FIN 16
#define NLAYER 5
#define BN_EPS 1e-5f

typedef __attribute__((ext_vector_type(8))) _Float16 f16x8;
typedef __attribute__((ext_vector_type(2))) __fp16 fp16v2;
typedef __attribute__((ext_vector_type(4))) float f32x4;
typedef unsigned short ushort_t;

union h2u { fp16v2 h; unsigned u; };
union hu  { _Float16 h; ushort_t u; };

// pack 2 floats to 2 fp16 with round-to-nearest
__device__ __forceinline__ unsigned pkrn(float x, float y) {
    hu A; A.h = (_Float16)x;
    hu B; B.h = (_Float16)y;
    return (unsigned)A.u | ((unsigned)B.u << 16);
}

// accumulate 8 fp16 (packed in uint4) into f[0..7]
__device__ __forceinline__ void acc8(float* f, uint4 v) {
    h2u c0, c1, c2, c3;
    c0.u = v.x; c1.u = v.y; c2.u = v.z; c3.u = v.w;
    f[0] += (float)c0.h.x; f[1] += (float)c0.h.y;
    f[2] += (float)c1.h.x; f[3] += (float)c1.h.y;
    f[4] += (float)c2.h.x; f[5] += (float)c2.h.y;
    f[6] += (float)c3.h.x; f[7] += (float)c3.h.y;
}

// LDS tile address: logical [node][byteoff 0..255], XOR-swizzled for bank spread.
__device__ __forceinline__ unsigned swz(int node, unsigned byteoff) {
    return (unsigned)(node * 256 + byteoff) ^ (((unsigned)node & 7u) << 4);
}

// ---------------- graph preprocessing ----------------

__global__ __launch_bounds__(256) void k_gstart(const int* __restrict__ batch,
                                                int* __restrict__ gs, int N, int G) {
    int i = blockIdx.x * 256 + threadIdx.x;
    if (i >= N) return;
    if (i == 0) gs[0] = 0;
    else { int b = batch[i]; if (b != batch[i - 1]) gs[b] = i; }
    if (i == N - 1) gs[G] = N;
}

__global__ __launch_bounds__(256) void k_zero_i32(int* __restrict__ p, int n) {
    int i = blockIdx.x * 256 + threadIdx.x;
    if (i < n) p[i] = 0;
}

__global__ __launch_bounds__(256) void k_fill_i32(int* __restrict__ p, int val, int n) {
    int i = blockIdx.x * 256 + threadIdx.x;
    if (i < n) p[i] = val;
}

__global__ __launch_bounds__(256) void k_zero_f32(float* __restrict__ p, int n) {
    int i = blockIdx.x * 256 + threadIdx.x;
    if (i < n) p[i] = 0.f;
}

__global__ __launch_bounds__(128) void k_zero_dummy(ushort_t* __restrict__ a,
                                                    ushort_t* __restrict__ b, int N) {
    int i = threadIdx.x;
    a[(size_t)N * EMB + i] = 0;
    b[(size_t)N * EMB + i] = 0;
}

__global__ __launch_bounds__(256) void k_hist(const int* __restrict__ dst, int* __restrict__ cnt, int E) {
    int e = blockIdx.x * 256 + threadIdx.x;
    if (e < E) atomicAdd(&cnt[dst[e]], 1);
}

// scans over N+1 entries; per-node counts PADDED to multiples of 4 -> rs[N] = padded total
__global__ __launch_bounds__(256) void k_scan1(const int* __restrict__ cnt, int* __restrict__ rs,
                                               int* __restrict__ partials, int N) {
    __shared__ int tsum[256];
    int t = threadIdx.x;
    int base = blockIdx.x * 1024 + t * 4;
    int c[4];
    #pragma unroll
    for (int j = 0; j < 4; j++) c[j] = (base + j < N) ? ((cnt[base + j] + 3) & ~3) : 0;
    int s = c[0] + c[1] + c[2] + c[3];
    tsum[t] = s;
    __syncthreads();
    for (int off = 1; off < 256; off <<= 1) {
        int v = (t >= off) ? tsum[t - off] : 0;
        __syncthreads();
        tsum[t] += v;
        __syncthreads();
    }
    int run = tsum[t] - s;
    if (t == 255) partials[blockIdx.x] = tsum[255];
    #pragma unroll
    for (int j = 0; j < 4; j++) {
        if (base + j <= N) rs[base + j] = run;
        run += c[j];
    }
}

__global__ __launch_bounds__(256) void k_scan2(int* __restrict__ partials, int NB) {
    __shared__ int tmp[256];
    int t = threadIdx.x;
    int v = (t < NB) ? partials[t] : 0;
    tmp[t] = v;
    __syncthreads();
    for (int off = 1; off < 256; off <<= 1) {
        int u = (t >= off) ? tmp[t - off] : 0;
        __syncthreads();
        tmp[t] += u;
        __syncthreads();
    }
    if (t < NB) partials[t] = tmp[t] - v;
}

__global__ __launch_bounds__(256) void k_scan3(int* __restrict__ rs, const int* __restrict__ partials,
                                               int* __restrict__ cur_off, int N) {
    int t = threadIdx.x;
    int base = blockIdx.x * 1024 + t * 4;
    int add = partials[blockIdx.x];
    #pragma unroll
    for (int j = 0; j < 4; j++) {
        int i = base + j;
        if (i <= N) {
            int v = rs[i] + add;
            rs[i] = v;
            if (i < N) cur_off[i] = v;
        }
    }
}

__global__ __launch_bounds__(256) void k_fillslots(const int* __restrict__ src, const int* __restrict__ dst,
                                                   int* __restrict__ cur_off, int* __restrict__ csr_src, int E) {
    int e = blockIdx.x * 256 + threadIdx.x;
    if (e >= E) return;
    int d = dst[e];
    int pos = atomicAdd(&cur_off[d], 1);
    csr_src[pos] = src[e];
}

// ---------------- weight prep: fold BN, transpose, convert to fp16 (RN) ----------------

__global__ __launch_bounds__(256) void k_prep(
        const float* __restrict__ init_w1, const float* __restrict__ init_b1,
        const float* __restrict__ b1s, const float* __restrict__ b1b,
        const float* __restrict__ b1m, const float* __restrict__ b1v,
        const float* __restrict__ init_w2, const float* __restrict__ init_b2,
        const float* __restrict__ i_s, const float* __restrict__ i_b,
        const float* __restrict__ i_m, const float* __restrict__ i_v,
        const float* __restrict__ lw1, const float* __restrict__ lb1,
        const float* __restrict__ l1s, const float* __restrict__ l1b,
        const float* __restrict__ l1m, const float* __restrict__ l1v,
        const float* __restrict__ lw2, const float* __restrict__ lb2,
        const float* __restrict__ l2s, const float* __restrict__ l2b,
        const float* __restrict__ l2m, const float* __restrict__ l2v,
        const float* __restrict__ ilin_w, const float* __restrict__ ilin_b,
        ushort_t* __restrict__ WT, float* __restrict__ biasf,
        float* __restrict__ W1f, float* __restrict__ bias1f,
        ushort_t* __restrict__ WzT, float* __restrict__ biasz) {
    int j = blockIdx.x;
    int t = threadIdx.x;
    __shared__ float alpha[EMB];

    if (j == 12) {
        if (t < 16) biasz[t] = (t < CDIM) ? ilin_b[t] : 0.f;
        for (int i = t; i < 16 * EMB; i += 256) {
            int f = i >> 7, k = i & 127;
            float w = (f < CDIM) ? ilin_w[k * CDIM + f] : 0.f;
            hu x; x.h = (_Float16)w;
            WzT[i] = x.u;
        }
        return;
    }
    if (j == 11) {
        if (t < EMB) {
            float a = b1s[t] * rsqrtf(b1v[t] + BN_EPS);
            alpha[t] = a;
            bias1f[t] = init_b1[t] * a + (b1b[t] - b1m[t] * a);
        }
        __syncthreads();
        for (int i = t; i < FIN * EMB; i += 256) W1f[i] = init_w1[i] * alpha[i & 127];
        return;
    }

    const float *W, *lb, *s, *bb, *m, *v;
    if (j == 0)      { W = init_w2;            lb = init_b2;        s = i_s;           bb = i_b;           m = i_m;           v = i_v; }
    else if (j <= 5) { int l = j - 1; W = lw1 + l * 16384; lb = lb1 + l * 128; s = l1s + l * 128; bb = l1b + l * 128; m = l1m + l * 128; v = l1v + l * 128; }
    else             { int l = j - 6; W = lw2 + l * 16384; lb = lb2 + l * 128; s = l2s + l * 128; bb = l2b + l * 128; m = l2m + l * 128; v = l2v + l * 128; }
    if (t < EMB) {
        float a = s[t] * rsqrtf(v[t] + BN_EPS);
        alpha[t] = a;
        biasf[j * EMB + t] = lb[t] * a + (bb[t] - m[t] * a);
    }
    __syncthreads();
    for (int i = t; i < EMB * EMB; i += 256) {
        int k = i >> 7, f = i & 127;
        float w = W[i] * alpha[f];
        hu x; x.h = (_Float16)w;
        WT[j * 16384 + f * 128 + k] = x.u;
    }
}

// ---------------- fused layer kernel ----------------
// h stored globally as fp16 [N+1][128] (row N = zero dummy for CSR pads).
// SINGLE-fp16 LDS path: aggregate/intermediate rounded RN once; 1 MFMA per (s,sub) per gemm.
// MODE 0 (init, NT=16): phaseA = relu(bn(x@W1)); gemm(init_w2) -> h(fp16) + LDSB; wave0: z-gemm
// MODE 1 (GIN, NT=32):  phaseA = (1+eps)h + sum_nbr h (padded CSR batch-4);
//                       gemm1 -> LDSB; gemm2 -> h'(fp16, opt) + fused shfl-segmax -> smax.

template<int MODE>
__global__ __launch_bounds__(512, 4) void k_layer(
        const float* __restrict__ xin, const ushort_t* __restrict__ hin,
        ushort_t* __restrict__ hout, float* __restrict__ z,
        const ushort_t* __restrict__ W1T, const float* __restrict__ b1,
        const ushort_t* __restrict__ W2T, const float* __restrict__ b2,
        const ushort_t* __restrict__ WzT, const float* __restrict__ bz,
        const float* __restrict__ W1f, const float* __restrict__ b1f,
        const int* __restrict__ rs, const int* __restrict__ csr, const float* __restrict__ epsp,
        const int* __restrict__ batch, float* __restrict__ smax,
        int ntiles, int N) {
    constexpr int NT = (MODE == 1) ? 32 : 16;
    __shared__ ushort_t Aq[NT * 128], Bq[NT * 128];
    __shared__ float W1s[(MODE == 0) ? FIN * EMB : 1];

    const int t = threadIdx.x;
    const int w = t >> 6;
    const int lane = t & 63;
    const int col = lane & 15, kg = lane >> 4;

    if (MODE == 0) {
        for (int i = t; i < FIN * EMB; i += 512) W1s[i] = W1f[i];
        __syncthreads();
    }

    // register-resident weight fragments (single fp16 per matrix: 16 regs each)
    f16x8 w1f[4], w2f[4], wzf[4];
    #pragma unroll
    for (int s = 0; s < 4; s++) {
        int off = (w * 16 + col) * EMB + s * 32 + kg * 8;
        w1f[s] = *(const f16x8*)(W1T + off);
        if (MODE == 1) w2f[s] = *(const f16x8*)(W2T + off);
        if (MODE == 0) {
            int zoff = col * EMB + s * 32 + kg * 8;
            wzf[s] = *(const f16x8*)(WzT + zoff);
        }
    }
    float4 bv1 = *(const float4*)&b1[w * 16 + kg * 4];
    float4 bv2, bvz;
    if (MODE == 1) bv2 = *(const float4*)&b2[w * 16 + kg * 4];
    if (MODE == 0) bvz = *(const float4*)&bz[kg * 4];
    float se = (MODE == 1) ? (1.f + epsp[0]) : 0.f;

    for (int tile = blockIdx.x; tile < ntiles; tile += gridDim.x) {
        const int n0 = tile * NT;

        // ---- phase A -> LDSA (single fp16 of the fp32 aggregate) ----
        if (MODE == 1) {
            const int nl = t >> 4, q2 = t & 15;   // node-local 0..31, 8 feats
            const int nc = min(n0 + nl, N - 1);
            const uint4* hp = (const uint4*)hin;  // row = 16 uint4 (256B)
            uint4 sv = hp[(size_t)nc * 16 + q2];
            float a[8] = {0.f, 0.f, 0.f, 0.f, 0.f, 0.f, 0.f, 0.f};
            acc8(a, sv);
            #pragma unroll
            for (int i = 0; i < 8; i++) a[i] *= se;
            int p = rs[nc], pe = rs[nc + 1];
            // padded CSR: (pe-p)%4==0; pad entries -> zero row N
            for (; p < pe; p += 4) {
                uint4 idx = *(const uint4*)&csr[p];
                uint4 v0 = hp[(size_t)idx.x * 16 + q2];
                uint4 v1 = hp[(size_t)idx.y * 16 + q2];
                uint4 v2 = hp[(size_t)idx.z * 16 + q2];
                uint4 v3 = hp[(size_t)idx.w * 16 + q2];
                acc8(a, v0); acc8(a, v1); acc8(a, v2); acc8(a, v3);
            }
            uint4 H;
            H.x = pkrn(a[0], a[1]); H.y = pkrn(a[2], a[3]);
            H.z = pkrn(a[4], a[5]); H.w = pkrn(a[6], a[7]);
            *(uint4*)((char*)Aq + swz(nl, (unsigned)q2 * 16)) = H;
        } else {
            const int nl = t >> 5, q = t & 31;    // 16 nodes x 4 feats
            const int nc = min(n0 + nl, N - 1);
            float4 ba = *(const float4*)&b1f[q * 4];
            float a0 = ba.x, a1 = ba.y, a2 = ba.z, a3 = ba.w;
            const float* xp = xin + (size_t)nc * FIN;
            #pragma unroll
            for (int k = 0; k < FIN; k++) {
                float xk = xp[k];
                float4 wv = *(const float4*)&W1s[k * EMB + q * 4];
                a0 += xk * wv.x; a1 += xk * wv.y; a2 += xk * wv.z; a3 += xk * wv.w;
            }
            a0 = fmaxf(a0, 0.f); a1 = fmaxf(a1, 0.f); a2 = fmaxf(a2, 0.f); a3 = fmaxf(a3, 0.f);
            uint2 H;
            H.x = pkrn(a0, a1); H.y = pkrn(a2, a3);
            *(uint2*)((char*)Aq + swz(nl, (unsigned)q * 8)) = H;
        }
        __syncthreads();

        // ---- phase B: gemm1 from LDSA -> LDSB (MODE0: + hout fp16 store) ----
        {
            f32x4 aA0 = (f32x4){0.f, 0.f, 0.f, 0.f}, aA1 = aA0;
            #pragma unroll
            for (int s = 0; s < 4; s++) {
                unsigned bo = (unsigned)((s * 32 + kg * 8) * 2);
                f16x8 x0 = *(const f16x8*)((const char*)Aq + swz(col, bo));
                aA0 = __builtin_amdgcn_mfma_f32_16x16x32_f16(w1f[s], x0, aA0, 0, 0, 0);
                if (MODE == 1) {
                    f16x8 x1 = *(const f16x8*)((const char*)Aq + swz(col + 16, bo));
                    aA1 = __builtin_amdgcn_mfma_f32_16x16x32_f16(w1f[s], x1, aA1, 0, 0, 0);
                }
            }
            #pragma unroll
            for (int sub = 0; sub < ((MODE == 1) ? 2 : 1); sub++) {
                f32x4 aa = sub ? aA1 : aA0;
                float y0 = fmaxf(aa[0] + bv1.x, 0.f);
                float y1 = fmaxf(aa[1] + bv1.y, 0.f);
                float y2 = fmaxf(aa[2] + bv1.z, 0.f);
                float y3 = fmaxf(aa[3] + bv1.w, 0.f);
                uint2 P; P.x = pkrn(y0, y1); P.y = pkrn(y2, y3);
                if (MODE == 0) {
                    int onode = n0 + col;
                    if (onode < N)
                        *(uint2*)&hout[(size_t)onode * EMB + w * 16 + kg * 4] = P;
                }
                *(uint2*)((char*)Bq + swz(col + sub * 16, (unsigned)(w * 32 + kg * 8))) = P;
            }
        }
        __syncthreads();

        // ---- phase D: gemm2 + fused segmax (MODE1) / z-gemm (MODE0, wave0) ----
        if (MODE == 1) {
            f32x4 aA0 = (f32x4){0.f, 0.f, 0.f, 0.f}, aA1 = aA0;
            #pragma unroll
            for (int s = 0; s < 4; s++) {
                unsigned bo = (unsigned)((s * 32 + kg * 8) * 2);
                f16x8 x0 = *(const f16x8*)((const char*)Bq + swz(col, bo));
                f16x8 x1 = *(const f16x8*)((const char*)Bq + swz(col + 16, bo));
                aA0 = __builtin_amdgcn_mfma_f32_16x16x32_f16(w2f[s], x0, aA0, 0, 0, 0);
                aA1 = __builtin_amdgcn_mfma_f32_16x16x32_f16(w2f[s], x1, aA1, 0, 0, 0);
            }
            #pragma unroll
            for (int sub = 0; sub < 2; sub++) {
                f32x4 aa = sub ? aA1 : aA0;
                int onode = n0 + col + sub * 16;
                float o0 = fmaxf(aa[0] + bv2.x, 0.f);
                float o1 = fmaxf(aa[1] + bv2.y, 0.f);
                float o2 = fmaxf(aa[2] + bv2.z, 0.f);
                float o3 = fmaxf(aa[3] + bv2.w, 0.f);
                if (hout && onode < N) {
                    uint2 P; P.x = pkrn(o0, o1); P.y = pkrn(o2, o3);
                    *(uint2*)&hout[(size_t)onode * EMB + w * 16 + kg * 4] = P;
                }
                // fused segment-max: width-16 segmented scan-max, tail lanes do atomicMax.
                bool valid = onode < N;
                float v0 = valid ? o0 : 0.f, v1 = valid ? o1 : 0.f;
                float v2 = valid ? o2 : 0.f, v3 = valid ? o3 : 0.f;
                int g = batch[min(onode, N - 1)];
                #pragma unroll
                for (int off = 1; off < 16; off <<= 1) {
                    float u0 = __shfl_up(v0, off, 16);
                    float u1 = __shfl_up(v1, off, 16);
                    float u2 = __shfl_up(v2, off, 16);
                    float u3 = __shfl_up(v3, off, 16);
                    int gg = __shfl_up(g, off, 16);
                    bool take = (col >= off) && (gg == g);
                    if (take) {
                        v0 = fmaxf(v0, u0); v1 = fmaxf(v1, u1);
                        v2 = fmaxf(v2, u2); v3 = fmaxf(v3, u3);
                    }
                }
                int gn = __shfl_down(g, 1, 16);
                bool tail = (col == 15) || (gn != g);
                if (tail) {
                    unsigned* sp = (unsigned*)&smax[(size_t)g * EMB + w * 16 + kg * 4];
                    atomicMax(sp + 0, __float_as_uint(v0));
                    atomicMax(sp + 1, __float_as_uint(v1));
                    atomicMax(sp + 2, __float_as_uint(v2));
                    atomicMax(sp + 3, __float_as_uint(v3));
                }
            }
        } else if (w == 0) {
            f32x4 aA0 = (f32x4){0.f, 0.f, 0.f, 0.f};
            #pragma unroll
            for (int s = 0; s < 4; s++) {
                unsigned bo = (unsigned)((s * 32 + kg * 8) * 2);
                f16x8 x0 = *(const f16x8*)((const char*)Bq + swz(col, bo));
                aA0 = __builtin_amdgcn_mfma_f32_16x16x32_f16(wzf[s], x0, aA0, 0, 0, 0);
            }
            int onode = n0 + col;
            if (onode < N && kg < 3) {
                float4 o;
                o.x = aA0[0] + bvz.x;
                o.y = aA0[1] + bvz.y;
                o.z = aA0[2] + bvz.z;
                o.w = aA0[3] + bvz.w;
                *(float4*)&z[(size_t)onode * CDIM + kg * 4] = o;
            }
        }
        // no trailing barrier: next-tile A-writes gated by this tile's post-B barrier
        // (A last read in phase B); B-writes gated by next post-A barrier.
    }
}

// ---------------- readouts ----------------

__global__ __launch_bounds__(64) void k_zmax(const float* __restrict__ z, const int* __restrict__ gs,
        float* __restrict__ out, int G) {
    int g = blockIdx.x;
    int t = threadIdx.x;
    if (t >= CDIM) return;
    int s0 = gs[g], e0 = gs[g + 1];
    float m = -INFINITY;
    for (int n = s0; n < e0; n++) m = fmaxf(m, z[(size_t)n * CDIM + t]);
    out[g * CDIM + t] = m;
}

// out[g,c] += sum_l ( smax_l[g,:] @ llin_w[l] + llin_b[l] )
__global__ __launch_bounds__(128) void k_comb(const float* __restrict__ smax,
        const float* __restrict__ llin_w, const float* __restrict__ llin_b,
        float* __restrict__ out, int G) {
    int g = blockIdx.x;
    int t = threadIdx.x;
    __shared__ float mv[NLAYER][EMB];
    #pragma unroll
    for (int l = 0; l < NLAYER; l++)
        mv[l][t] = smax[((size_t)l * G + g) * EMB + t];
    __syncthreads();
    __shared__ float parts_[8][16];
    int c = t & 15, half = t >> 4;
    float acc = 0.f;
    if (c < CDIM) {
        #pragma unroll
        for (int l = 0; l < NLAYER; l++) {
            const float* Wl = llin_w + l * EMB * CDIM;
            #pragma unroll
            for (int kk = 0; kk < 16; kk++) {
                int k = half * 16 + kk;
                acc += mv[l][k] * Wl[k * CDIM + c];
            }
        }
    }
    parts_[half][c] = acc;
    __syncthreads();
    if (t < CDIM) {
        float s = 0.f;
        #pragma unroll
        for (int hh = 0; hh < 8; hh++) s += parts_[hh][t];
        #pragma unroll
        for (int l = 0; l < NLAYER; l++) s += llin_b[l * CDIM + t];
        out[g * CDIM + t] += s;
    }
}

// ---------------- launch ----------------

extern "C" void kernel_launch(void* const* d_in, const int* in_sizes, int n_in,
                              void* d_out, int out_size, void* d_ws, size_t ws_size,
                              hipStream_t stream) {
    const float* x        = (const float*)d_in[0];
    const int*   ei       = (const int*)d_in[1];
    const int*   batch    = (const int*)d_in[2];
    const float* init_w1  = (const float*)d_in[3];
    const float* init_b1  = (const float*)d_in[4];
    const float* ibn1_s   = (const float*)d_in[5];
    const float* ibn1_b   = (const float*)d_in[6];
    const float* ibn1_m   = (const float*)d_in[7];
    const float* ibn1_v   = (const float*)d_in[8];
    const float* init_w2  = (const float*)d_in[9];
    const float* init_b2  = (const float*)d_in[10];
    const float* ibn2_s   = (const float*)d_in[11];
    const float* ibn2_b   = (const float*)d_in[12];
    const float* ibn2_m   = (const float*)d_in[13];
    const float* ibn2_v   = (const float*)d_in[14];
    const float* ilin_w   = (const float*)d_in[15];
    const float* ilin_b   = (const float*)d_in[16];
    const float* eps      = (const float*)d_in[17];
    const float* lw1      = (const float*)d_in[18];
    const float* lb1      = (const float*)d_in[19];
    const float* lbn1_s   = (const float*)d_in[20];
    const float* lbn1_b   = (const float*)d_in[21];
    const float* lbn1_m   = (const float*)d_in[22];
    const float* lbn1_v   = (const float*)d_in[23];
    const float* lw2      = (const float*)d_in[24];
    const float* lb2      = (const float*)d_in[25];
    const float* lbn2_s   = (const float*)d_in[26];
    const float* lbn2_b   = (const float*)d_in[27];
    const float* lbn2_m   = (const float*)d_in[28];
    const float* lbn2_v   = (const float*)d_in[29];
    const float* llin_w   = (const float*)d_in[30];
    const float* llin_b   = (const float*)d_in[31];

    const int N = in_sizes[0] / FIN;
    const int E = in_sizes[1] / 2;
    const int G = out_size / CDIM;
    const int* src = ei;
    const int* dst = ei + E;
    float* out = (float*)d_out;

    const int EPADMAX = E + 3 * N;

    char* wp = (char*)d_ws;
    auto alloc = [&](size_t bytes) { char* p = wp; wp += (bytes + 255) & ~(size_t)255; return p; };
    ushort_t* WT    = (ushort_t*)alloc((size_t)11 * 16384 * 2);
    float*    biasf = (float*)alloc(11 * EMB * 4);
    float*    W1f   = (float*)alloc(FIN * EMB * 4);
    float*    bias1f= (float*)alloc(EMB * 4);
    ushort_t* WzT   = (ushort_t*)alloc(16 * EMB * 2);
    float*    biasz = (float*)alloc(16 * 4);
    int*      gs    = (int*)alloc((size_t)(G + 1) * 4);
    int*      rs    = (int*)alloc((size_t)(N + 1) * 4);
    int*      curoff= (int*)alloc((size_t)N * 4);
    int*      csr   = (int*)alloc((size_t)EPADMAX * 4);
    int*      parts = (int*)alloc(256 * 4);
    float*    zbuf  = (float*)alloc((size_t)N * CDIM * 4);
    float*    smax  = (float*)alloc((size_t)NLAYER * G * EMB * 4);
    ushort_t* bufP  = (ushort_t*)alloc((size_t)(N + 1) * EMB * 2);   // row N = zero dummy
    ushort_t* bufQ  = (ushort_t*)alloc((size_t)(N + 1) * EMB * 2);
    int*      cnt   = csr;           // alias: cnt dead before csr pre-filled

    const int NB = (N + 1 + 1023) / 1024;
    const int ntiles16 = (N + 15) / 16;
    const int ntiles32 = (N + 31) / 32;
    const int GRID = 2084;

    // per-call inits (smax: atomicMax with non-negative floats; zero is identity)
    k_zero_f32<<<((NLAYER * G * EMB) + 255) / 256, 256, 0, stream>>>(smax, NLAYER * G * EMB);
    k_zero_dummy<<<1, 128, 0, stream>>>(bufP, bufQ, N);

    // graph prep (padded CSR) + weight prep
    k_zero_i32<<<(N + 255) / 256, 256, 0, stream>>>(cnt, N);
    k_hist<<<(E + 255) / 256, 256, 0, stream>>>(dst, cnt, E);
    k_scan1<<<NB, 256, 0, stream>>>(cnt, rs, parts, N);
    k_scan2<<<1, 256, 0, stream>>>(parts, NB);
    k_scan3<<<NB, 256, 0, stream>>>(rs, parts, curoff, N);
    k_fill_i32<<<(EPADMAX + 255) / 256, 256, 0, stream>>>(csr, N, EPADMAX);  // pads -> zero row N
    k_fillslots<<<(E + 255) / 256, 256, 0, stream>>>(src, dst, curoff, csr, E);
    k_gstart<<<(N + 255) / 256, 256, 0, stream>>>(batch, gs, N, G);
    k_prep<<<13, 256, 0, stream>>>(init_w1, init_b1, ibn1_s, ibn1_b, ibn1_m, ibn1_v,
                                   init_w2, init_b2, ibn2_s, ibn2_b, ibn2_m, ibn2_v,
                                   lw1, lb1, lbn1_s, lbn1_b, lbn1_m, lbn1_v,
                                   lw2, lb2, lbn2_s, lbn2_b, lbn2_m, lbn2_v,
                                   ilin_w, ilin_b,
                                   WT, biasf, W1f, bias1f, WzT, biasz);

    // init MLP + z (fused) -> h(fp16) in bufQ, z in zbuf
    k_layer<0><<<GRID, 512, 0, stream>>>(x, nullptr, bufQ, zbuf,
                                         WT, biasf,
                                         nullptr, nullptr,
                                         WzT, biasz,
                                         W1f, bias1f,
                                         nullptr, nullptr, nullptr,
                                         nullptr, nullptr, ntiles16, N);
    k_zmax<<<G, 64, 0, stream>>>(zbuf, gs, out, G);

    ushort_t* cur = bufQ;
    ushort_t* oth = bufP;
    for (int l = 0; l < NLAYER; l++) {
        ushort_t* houtl = (l == NLAYER - 1) ? nullptr : oth;   // last layer: segmax only
        k_layer<1><<<GRID, 512, 0, stream>>>(nullptr, cur, houtl, nullptr,
                                             WT + (size_t)(1 + l) * 16384, biasf + (1 + l) * EMB,
                                             WT + (size_t)(6 + l) * 16384, biasf + (6 + l) * EMB,
                                             nullptr, nullptr,
                                             nullptr, nullptr,
                                             rs, csr, eps + l,
                                             batch, smax + (size_t)l * G * EMB, ntiles32, N);
        ushort_t* tmp = cur; cur = oth; oth = tmp;
    }
    k_comb<<<G, 128, 0, stream>>>(smax, llin_w, llin_b, out, G);
}